// Round 1
// baseline (689.637 us; speedup 1.0000x reference)
//
#include <hip/hip_runtime.h>
#include <hip/hip_bf16.h>
#include <math.h>

// GCN 2-layer forward:
//   h1 = D^-1/2 (A+I) D^-1/2 (x@W1) + b1 ; relu
//   h2 = D^-1/2 (A+I) D^-1/2 (h1@W2) + b2 ; log_softmax
// Pre-scale trick: h1s[n] = (x@W1)[n]*dinv[n]; edge contribution = h1s[src]*dinv[dst];
// self-loop = h1s[n]*dinv[n] used to INITIALIZE the accumulator (no zeroing pass).

#define F_IN 128
#define H1 16
#define C_OUT 2

__global__ void k_deg_init(float* __restrict__ deg, int N) {
    int i = blockIdx.x * blockDim.x + threadIdx.x;
    if (i < N) deg[i] = 1.0f;  // self-loop contributes 1 to every node's degree
}

__global__ void k_deg_accum(const int* __restrict__ dst, float* __restrict__ deg, int E) {
    int i = blockIdx.x * blockDim.x + threadIdx.x;
    if (i < E) unsafeAtomicAdd(deg + dst[i], 1.0f);
}

__global__ void k_dinv(float* __restrict__ deg, int N) {
    int i = blockIdx.x * blockDim.x + threadIdx.x;
    if (i < N) deg[i] = rsqrtf(deg[i]);  // deg >= 1 always, no zero guard needed
}

// x [N,128] @ W1 [128,16] -> h1s = h*dinv, agg1 init = h*dinv^2 (self loop)
// block: 256 threads = 16 nodes x 16 out-features; x tile + W1 staged in LDS.
__global__ __launch_bounds__(256) void k_gemm1(
    const float* __restrict__ x, const float* __restrict__ W1,
    const float* __restrict__ dinv, float* __restrict__ h1s,
    float* __restrict__ agg1, int N) {
    __shared__ float w[F_IN * H1];    // 8 KB
    __shared__ float xt[16 * F_IN];   // 8 KB
    int tid = threadIdx.x;
    int node0 = blockIdx.x * 16;

    const float4* W14 = (const float4*)W1;
    float4* w4 = (float4*)w;
    for (int i = tid; i < F_IN * H1 / 4; i += 256) w4[i] = W14[i];

    const float4* x4 = (const float4*)x;
    float4* xt4 = (float4*)xt;
    for (int i = tid; i < 16 * F_IN / 4; i += 256) {
        int r = i >> 5;  // 32 float4 per row
        int node = node0 + r;
        xt4[i] = (node < N) ? x4[(size_t)node * 32 + (i & 31)]
                            : make_float4(0.f, 0.f, 0.f, 0.f);
    }
    __syncthreads();

    int nsub = tid >> 4, f = tid & 15;
    int node = node0 + nsub;
    if (node < N) {
        const float* xr = xt + nsub * F_IN;
        float acc = 0.0f;
        #pragma unroll 16
        for (int k = 0; k < F_IN; ++k)
            acc = fmaf(xr[k], w[k * H1 + f], acc);
        float dv = dinv[node];
        float s = acc * dv;
        h1s[node * H1 + f] = s;
        agg1[node * H1 + f] = s * dv;  // self-loop term initializes accumulator
    }
}

// one thread per (edge, feature): agg1[dst,f] += h1s[src,f] * dinv[dst]
__global__ __launch_bounds__(256) void k_edge1(
    const int* __restrict__ src, const int* __restrict__ dst,
    const float* __restrict__ h1s, const float* __restrict__ dinv,
    float* __restrict__ agg1, int ET) {
    int t = blockIdx.x * blockDim.x + threadIdx.x;
    if (t >= ET) return;
    int e = t >> 4;
    int f = t & 15;
    int s = src[e], d = dst[e];
    float v = h1s[s * H1 + f] * dinv[d];
    unsafeAtomicAdd(agg1 + d * H1 + f, v);
}

// per node: v = relu(agg1+b1); h2 = v@W2; h2s = h2*dinv; agg2 init = h2*dinv^2
__global__ __launch_bounds__(256) void k_layer2(
    const float* __restrict__ agg1, const float* __restrict__ b1,
    const float* __restrict__ W2, const float* __restrict__ dinv,
    float* __restrict__ h2s, float* __restrict__ agg2, int N) {
    int n = blockIdx.x * blockDim.x + threadIdx.x;
    if (n >= N) return;
    const float4* a4 = (const float4*)(agg1 + (size_t)n * H1);
    float c0 = 0.f, c1 = 0.f;
    #pragma unroll
    for (int q = 0; q < 4; ++q) {
        float4 a = a4[q];
        float vv[4] = {a.x, a.y, a.z, a.w};
        #pragma unroll
        for (int j = 0; j < 4; ++j) {
            int f = q * 4 + j;
            float v = fmaxf(vv[j] + b1[f], 0.0f);
            c0 = fmaf(v, W2[f * C_OUT + 0], c0);
            c1 = fmaf(v, W2[f * C_OUT + 1], c1);
        }
    }
    float dv = dinv[n];
    float2 hs; hs.x = c0 * dv; hs.y = c1 * dv;
    ((float2*)h2s)[n] = hs;
    float2 ag; ag.x = hs.x * dv; ag.y = hs.y * dv;
    ((float2*)agg2)[n] = ag;
}

// one thread per edge: agg2[dst,c] += h2s[src,c]*dinv[dst], c=0,1
__global__ __launch_bounds__(256) void k_edge2(
    const int* __restrict__ src, const int* __restrict__ dst,
    const float* __restrict__ h2s, const float* __restrict__ dinv,
    float* __restrict__ agg2, int E) {
    int e = blockIdx.x * blockDim.x + threadIdx.x;
    if (e >= E) return;
    int s = src[e], d = dst[e];
    float nd = dinv[d];
    float2 hv = ((const float2*)h2s)[s];
    unsafeAtomicAdd(agg2 + d * C_OUT + 0, hv.x * nd);
    unsafeAtomicAdd(agg2 + d * C_OUT + 1, hv.y * nd);
}

// out[n,:] = log_softmax(agg2[n,:] + b2)
__global__ __launch_bounds__(256) void k_final(
    const float* __restrict__ agg2, const float* __restrict__ b2,
    float* __restrict__ out, int N) {
    int n = blockIdx.x * blockDim.x + threadIdx.x;
    if (n >= N) return;
    float2 a = ((const float2*)agg2)[n];
    float a0 = a.x + b2[0];
    float a1 = a.y + b2[1];
    float m = fmaxf(a0, a1);
    float lse = m + logf(expf(a0 - m) + expf(a1 - m));
    float2 o; o.x = a0 - lse; o.y = a1 - lse;
    ((float2*)out)[n] = o;
}

extern "C" void kernel_launch(void* const* d_in, const int* in_sizes, int n_in,
                              void* d_out, int out_size, void* d_ws, size_t ws_size,
                              hipStream_t stream) {
    const float* x  = (const float*)d_in[0];
    const int* ei   = (const int*)d_in[1];
    const float* W1 = (const float*)d_in[2];
    const float* b1 = (const float*)d_in[3];
    const float* W2 = (const float*)d_in[4];
    const float* b2 = (const float*)d_in[5];
    float* out = (float*)d_out;

    const int N = in_sizes[0] / F_IN;     // 100000
    const int E = in_sizes[1] / 2;        // 3200000
    const int* src = ei;                  // edge_index[0]
    const int* dst = ei + E;              // edge_index[1]

    // workspace layout (floats): dinv[N] | h1s[16N] | agg1[16N] | h2s[2N] | agg2[2N]
    float* ws   = (float*)d_ws;
    float* dinv = ws;
    float* h1s  = dinv + N;
    float* agg1 = h1s + (size_t)N * H1;
    float* h2s  = agg1 + (size_t)N * H1;
    float* agg2 = h2s + (size_t)N * C_OUT;

    int nbN = (N + 255) / 256;
    int nbE = (E + 255) / 256;

    k_deg_init<<<nbN, 256, 0, stream>>>(dinv, N);
    k_deg_accum<<<nbE, 256, 0, stream>>>(dst, dinv, E);
    k_dinv<<<nbN, 256, 0, stream>>>(dinv, N);
    k_gemm1<<<(N + 15) / 16, 256, 0, stream>>>(x, W1, dinv, h1s, agg1, N);
    int ET = E * H1;  // 51.2M, fits int32
    k_edge1<<<(ET + 255) / 256, 256, 0, stream>>>(src, dst, h1s, dinv, agg1, ET);
    k_layer2<<<nbN, 256, 0, stream>>>(agg1, b1, W2, dinv, h2s, agg2, N);
    k_edge2<<<nbE, 256, 0, stream>>>(src, dst, h2s, dinv, agg2, E);
    k_final<<<nbN, 256, 0, stream>>>(agg2, b2, out, N);
}

// Round 2
// 546.266 us; speedup vs baseline: 1.2625x; 1.2625x over previous
//
#include <hip/hip_runtime.h>
#include <hip/hip_bf16.h>
#include <math.h>

// GCN 2-layer forward, atomic-free restructure:
//   partition edges into buckets of NPB=128 dst nodes (counting sort, coalesced),
//   then per-bucket aggregation with LDS accumulators (LDS atomics only).
// Pre-scale: h1s[n] = (x@W1)[n]*dinv[n]; edge contribution = h1s[src]*dinv[dst];
// self-loop initializes the LDS accumulator. Layer-2 transform fused into agg1
// epilogue; log_softmax fused into agg2 epilogue.

#define F_IN 128
#define H1 16
#define C_OUT 2
#define NPB 128        // nodes per bucket (dst >> 7)
#define LOG_NPB 7
#define CH 16384       // edges per partition block
#define K_MAX 1024     // max buckets supported (N <= 131072)

// ---- partition pass A: per-chunk histogram of dst buckets ----
__global__ __launch_bounds__(256) void k_part_count(
    const int* __restrict__ dst0, int* __restrict__ cnt, int E, int K) {
    __shared__ int sc[K_MAX];
    for (int i = threadIdx.x; i < K; i += 256) sc[i] = 0;
    __syncthreads();
    int e0 = blockIdx.x * CH;
    int e1 = min(e0 + CH, E);
    for (int e = e0 + threadIdx.x; e < e1; e += 256)
        atomicAdd(&sc[dst0[e] >> LOG_NPB], 1);
    __syncthreads();
    int* out = cnt + (size_t)blockIdx.x * K;
    for (int i = threadIdx.x; i < K; i += 256) out[i] = sc[i];
}

// ---- partition pass B1: column-wise exclusive scan over chunks (in place), totals out ----
__global__ void k_colscan(int* __restrict__ cnt, int* __restrict__ tot, int nblk, int K) {
    int b = blockIdx.x * blockDim.x + threadIdx.x;
    if (b >= K) return;
    int run = 0;
    for (int blk = 0; blk < nblk; ++blk) {
        int idx = blk * K + b;
        int v = cnt[idx];
        cnt[idx] = run;
        run += v;
    }
    tot[b] = run;
}

// ---- partition pass B2: exclusive scan over bucket totals ----
__global__ __launch_bounds__(1024) void k_basescan(
    const int* __restrict__ tot, int* __restrict__ base_e, int K, int E) {
    __shared__ int s[K_MAX];
    int t = threadIdx.x;
    s[t] = (t < K) ? tot[t] : 0;
    __syncthreads();
    for (int off = 1; off < K_MAX; off <<= 1) {
        int v = (t >= off) ? s[t - off] : 0;
        __syncthreads();
        s[t] += v;
        __syncthreads();
    }
    if (t == 0) base_e[0] = 0;
    if (t < K) base_e[t + 1] = s[t];   // base_e[K] == E
}

// ---- partition pass C: scatter packed edges (src | dst_local<<24) into bucket order ----
__global__ __launch_bounds__(256) void k_scatter(
    const int* __restrict__ src0, const int* __restrict__ dst0,
    const int* __restrict__ cnt, const int* __restrict__ base_e,
    int* __restrict__ packed, int E, int K) {
    __shared__ int cur[K_MAX];
    const int* off = cnt + (size_t)blockIdx.x * K;
    for (int i = threadIdx.x; i < K; i += 256) cur[i] = base_e[i] + off[i];
    __syncthreads();
    int e0 = blockIdx.x * CH;
    int e1 = min(e0 + CH, E);
    for (int e = e0 + threadIdx.x; e < e1; e += 256) {
        int d = dst0[e];
        int b = d >> LOG_NPB;
        int pos = atomicAdd(&cur[b], 1);
        packed[pos] = src0[e] | ((d & (NPB - 1)) << 24);
    }
}

// ---- degree -> dinv, per bucket via LDS counters ----
__global__ __launch_bounds__(256) void k_deg(
    const int* __restrict__ packed, const int* __restrict__ base_e,
    float* __restrict__ dinv, int N) {
    __shared__ int cnt[NPB];
    int b = blockIdx.x;
    if (threadIdx.x < NPB) cnt[threadIdx.x] = 0;
    __syncthreads();
    int e0 = base_e[b], e1 = base_e[b + 1];
    for (int e = e0 + threadIdx.x; e < e1; e += 256)
        atomicAdd(&cnt[(packed[e] >> 24) & (NPB - 1)], 1);
    __syncthreads();
    int n = threadIdx.x;
    if (n < NPB) {
        int node = b * NPB + n;
        if (node < N) dinv[node] = rsqrtf((float)(cnt[n] + 1));  // +1 self-loop
    }
}

// ---- layer 1 GEMM: h1s = (x@W1)*dinv ----
__global__ __launch_bounds__(256) void k_gemm1(
    const float* __restrict__ x, const float* __restrict__ W1,
    const float* __restrict__ dinv, float* __restrict__ h1s, int N) {
    __shared__ float w[F_IN * H1];    // 8 KB
    __shared__ float xt[16 * F_IN];   // 8 KB
    int tid = threadIdx.x;
    int node0 = blockIdx.x * 16;

    const float4* W14 = (const float4*)W1;
    float4* w4 = (float4*)w;
    for (int i = tid; i < F_IN * H1 / 4; i += 256) w4[i] = W14[i];

    const float4* x4 = (const float4*)x;
    float4* xt4 = (float4*)xt;
    for (int i = tid; i < 16 * F_IN / 4; i += 256) {
        int r = i >> 5;  // 32 float4 per row
        int node = node0 + r;
        xt4[i] = (node < N) ? x4[(size_t)node * 32 + (i & 31)]
                            : make_float4(0.f, 0.f, 0.f, 0.f);
    }
    __syncthreads();

    int nsub = tid >> 4, f = tid & 15;
    int node = node0 + nsub;
    if (node < N) {
        const float* xr = xt + nsub * F_IN;
        float acc = 0.0f;
        #pragma unroll 16
        for (int k = 0; k < F_IN; ++k)
            acc = fmaf(xr[k], w[k * H1 + f], acc);
        h1s[node * H1 + f] = acc * dinv[node];
    }
}

// ---- layer 1 aggregation per bucket (LDS acc) + fused layer-2 transform ----
__global__ __launch_bounds__(256) void k_agg1(
    const int* __restrict__ packed, const int* __restrict__ base_e,
    const float* __restrict__ h1s, const float* __restrict__ dinv,
    const float* __restrict__ b1, const float* __restrict__ W2,
    float* __restrict__ h2s, int N) {
    __shared__ float acc[NPB][H1];   // 8 KB
    __shared__ float dl[NPB];
    int b = blockIdx.x;
    int base = b * NPB;
    int tid = threadIdx.x;
    if (tid < NPB) {
        int node = base + tid;
        dl[tid] = (node < N) ? dinv[node] : 0.f;
    }
    __syncthreads();
    // self-loop init: acc[n] = h1s[n] * dinv[n]
    for (int i = tid; i < NPB * H1; i += 256) {
        int n = i >> 4, f = i & 15;
        int node = base + n;
        acc[n][f] = (node < N) ? h1s[node * H1 + f] * dl[n] : 0.f;
    }
    __syncthreads();
    int e0 = base_e[b], e1 = base_e[b + 1];
    int f = tid & 15;
    for (int e = e0 + (tid >> 4); e < e1; e += 16) {
        int p = packed[e];
        int s = p & 0xFFFFFF;
        int d = (p >> 24) & (NPB - 1);
        float v = h1s[s * H1 + f] * dl[d];
        atomicAdd(&acc[d][f], v);
    }
    __syncthreads();
    // epilogue: v = relu(acc + b1); h2s = (v@W2)*dinv
    if (tid < NPB) {
        int node = base + tid;
        if (node < N) {
            float c0 = 0.f, c1 = 0.f;
            #pragma unroll
            for (int ff = 0; ff < H1; ++ff) {
                float v = fmaxf(acc[tid][ff] + b1[ff], 0.f);
                c0 = fmaf(v, W2[ff * C_OUT + 0], c0);
                c1 = fmaf(v, W2[ff * C_OUT + 1], c1);
            }
            float dv = dl[tid];
            ((float2*)h2s)[node] = make_float2(c0 * dv, c1 * dv);
        }
    }
}

// ---- layer 2 aggregation per bucket (LDS acc) + fused log_softmax ----
__global__ __launch_bounds__(256) void k_agg2(
    const int* __restrict__ packed, const int* __restrict__ base_e,
    const float* __restrict__ h2s, const float* __restrict__ dinv,
    const float* __restrict__ b2, float* __restrict__ out, int N) {
    __shared__ float acc[NPB][2];
    __shared__ float dl[NPB];
    int b = blockIdx.x;
    int base = b * NPB;
    int tid = threadIdx.x;
    if (tid < NPB) {
        int node = base + tid;
        float dv = (node < N) ? dinv[node] : 0.f;
        dl[tid] = dv;
        float2 h = (node < N) ? ((const float2*)h2s)[node] : make_float2(0.f, 0.f);
        acc[tid][0] = h.x * dv;   // self-loop init
        acc[tid][1] = h.y * dv;
    }
    __syncthreads();
    int e0 = base_e[b], e1 = base_e[b + 1];
    for (int e = e0 + tid; e < e1; e += 256) {
        int p = packed[e];
        int s = p & 0xFFFFFF;
        int d = (p >> 24) & (NPB - 1);
        float2 h = ((const float2*)h2s)[s];
        float dv = dl[d];
        atomicAdd(&acc[d][0], h.x * dv);
        atomicAdd(&acc[d][1], h.y * dv);
    }
    __syncthreads();
    if (tid < NPB) {
        int node = base + tid;
        if (node < N) {
            float a0 = acc[tid][0] + b2[0];
            float a1 = acc[tid][1] + b2[1];
            float m = fmaxf(a0, a1);
            float lse = m + logf(expf(a0 - m) + expf(a1 - m));
            ((float2*)out)[node] = make_float2(a0 - lse, a1 - lse);
        }
    }
}

extern "C" void kernel_launch(void* const* d_in, const int* in_sizes, int n_in,
                              void* d_out, int out_size, void* d_ws, size_t ws_size,
                              hipStream_t stream) {
    const float* x  = (const float*)d_in[0];
    const int* ei   = (const int*)d_in[1];
    const float* W1 = (const float*)d_in[2];
    const float* b1 = (const float*)d_in[3];
    const float* W2 = (const float*)d_in[4];
    const float* b2 = (const float*)d_in[5];
    float* out = (float*)d_out;

    const int N = in_sizes[0] / F_IN;     // 100000
    const int E = in_sizes[1] / 2;        // 3200000
    const int* src0 = ei;                 // edge_index[0]
    const int* dst0 = ei + E;             // edge_index[1]

    const int K = (N + NPB - 1) >> LOG_NPB;      // 782 buckets
    const int nblk = (E + CH - 1) / CH;          // 196 partition chunks

    // workspace layout (4B units):
    // dinv[N] | h1s[16N] | h2s[2N] | packed[E] | cnt[nblk*K] | tot[K] | base_e[K+1]
    float* ws     = (float*)d_ws;
    float* dinv   = ws;
    float* h1s    = dinv + N;
    float* h2s    = h1s + (size_t)N * H1;
    int*   packed = (int*)(h2s + (size_t)N * C_OUT);
    int*   cnt    = packed + E;
    int*   tot    = cnt + (size_t)nblk * K;
    int*   base_e = tot + K;

    k_part_count<<<nblk, 256, 0, stream>>>(dst0, cnt, E, K);
    k_colscan<<<(K + 255) / 256, 256, 0, stream>>>(cnt, tot, nblk, K);
    k_basescan<<<1, K_MAX, 0, stream>>>(tot, base_e, K, E);
    k_scatter<<<nblk, 256, 0, stream>>>(src0, dst0, cnt, base_e, packed, E, K);
    k_deg<<<K, 256, 0, stream>>>(packed, base_e, dinv, N);
    k_gemm1<<<(N + 15) / 16, 256, 0, stream>>>(x, W1, dinv, h1s, N);
    k_agg1<<<K, 256, 0, stream>>>(packed, base_e, h1s, dinv, b1, W2, h2s, N);
    k_agg2<<<K, 256, 0, stream>>>(packed, base_e, h2s, dinv, b2, out, N);
}

// Round 3
// 433.311 us; speedup vs baseline: 1.5916x; 1.2607x over previous
//
#include <hip/hip_runtime.h>
#include <hip/hip_bf16.h>
#include <math.h>

// GCN 2-layer forward, bucket-partitioned, latency-optimized:
//   edges sorted into buckets of NPB=128 dst nodes; aggregation uses LDS
//   accumulators with S segments/bucket (partials merged in a streaming pass).
// Pre-scale: h1s[n] = (x@W1)[n]*dinv[n]; edge contribution = h1s[src]*dinv[dst];
// self-loop handled in merge. Layer-2 transform fused into merge1; log_softmax
// fused into merge2.

#define F_IN 128
#define H1 16
#define C_OUT 2
#define NPB 128        // nodes per bucket (dst >> 7)
#define LOG_NPB 7
#define CH 4096        // edges per partition chunk
#define K_MAX 1024     // max buckets / max chunks supported

// ---- pass A: per-chunk histogram of dst buckets; cnt layout [K][nblk] ----
__global__ __launch_bounds__(256) void k_part_count(
    const int* __restrict__ dst0, int* __restrict__ cnt, int E, int K, int nblk) {
    __shared__ int sc[K_MAX];
    for (int i = threadIdx.x; i < K; i += 256) sc[i] = 0;
    __syncthreads();
    int e0 = blockIdx.x * CH, e1 = min(e0 + CH, E);
    for (int e = e0 + threadIdx.x; e < e1; e += 256)
        atomicAdd(&sc[((unsigned)dst0[e]) >> LOG_NPB], 1);
    __syncthreads();
    for (int b = threadIdx.x; b < K; b += 256)
        cnt[(size_t)b * nblk + blockIdx.x] = sc[b];
}

// ---- pass B1: per-bucket exclusive scan over chunks (block per bucket) ----
__global__ __launch_bounds__(1024) void k_colscan(
    int* __restrict__ cnt, int* __restrict__ tot, int nblk) {
    __shared__ int s[K_MAX];
    int t = threadIdx.x;
    int* row = cnt + (size_t)blockIdx.x * nblk;
    int own = (t < nblk) ? row[t] : 0;
    s[t] = own;
    __syncthreads();
    for (int off = 1; off < K_MAX; off <<= 1) {
        int v = (t >= off) ? s[t - off] : 0;
        __syncthreads();
        s[t] += v;
        __syncthreads();
    }
    if (t < nblk) row[t] = s[t] - own;              // exclusive
    if (t == 0) tot[blockIdx.x] = s[K_MAX - 1];     // total (zero-padded)
}

// ---- pass B2: exclusive scan over bucket totals -> base_e ----
__global__ __launch_bounds__(1024) void k_basescan(
    const int* __restrict__ tot, int* __restrict__ base_e, int K) {
    __shared__ int s[K_MAX];
    int t = threadIdx.x;
    s[t] = (t < K) ? tot[t] : 0;
    __syncthreads();
    for (int off = 1; off < K_MAX; off <<= 1) {
        int v = (t >= off) ? s[t - off] : 0;
        __syncthreads();
        s[t] += v;
        __syncthreads();
    }
    if (t == 0) base_e[0] = 0;
    if (t < K) base_e[t + 1] = s[t];   // base_e[K] == E
}

// ---- pass C: scatter packed edges (src | dst_local<<24) into bucket order ----
__global__ __launch_bounds__(256) void k_scatter(
    const int* __restrict__ src0, const int* __restrict__ dst0,
    const int* __restrict__ cnt, const int* __restrict__ base_e,
    int* __restrict__ packed, int E, int K, int nblk) {
    __shared__ int cur[K_MAX];
    int blk = blockIdx.x;
    for (int b = threadIdx.x; b < K; b += 256)
        cur[b] = base_e[b] + cnt[(size_t)b * nblk + blk];
    __syncthreads();
    int e0 = blk * CH, e1 = min(e0 + CH, E);
    for (int e = e0 + threadIdx.x; e < e1; e += 256) {
        unsigned d = (unsigned)dst0[e];
        int b = d >> LOG_NPB;
        int pos = atomicAdd(&cur[b], 1);
        packed[pos] = src0[e] | ((d & (NPB - 1)) << 24);
    }
}

// ---- degree -> dinv (block per bucket, 16 waves) ----
__global__ __launch_bounds__(1024) void k_deg(
    const int* __restrict__ packed, const int* __restrict__ base_e,
    float* __restrict__ dinv, int N) {
    __shared__ int cnt[NPB];
    int b = blockIdx.x, t = threadIdx.x;
    if (t < NPB) cnt[t] = 0;
    __syncthreads();
    int e0 = base_e[b], e1 = base_e[b + 1];
    for (int e = e0 + t; e < e1; e += 1024)
        atomicAdd(&cnt[(((unsigned)packed[e]) >> 24) & (NPB - 1)], 1);
    __syncthreads();
    if (t < NPB) {
        int node = b * NPB + t;
        if (node < N) dinv[node] = rsqrtf((float)(cnt[t] + 1));  // +1 self-loop
    }
}

// ---- layer 1 GEMM: h1s = (x@W1)*dinv ----
__global__ __launch_bounds__(256) void k_gemm1(
    const float* __restrict__ x, const float* __restrict__ W1,
    const float* __restrict__ dinv, float* __restrict__ h1s, int N) {
    __shared__ float w[F_IN * H1];    // 8 KB
    __shared__ float xt[16 * F_IN];   // 8 KB
    int tid = threadIdx.x;
    int node0 = blockIdx.x * 16;

    const float4* W14 = (const float4*)W1;
    float4* w4 = (float4*)w;
    for (int i = tid; i < F_IN * H1 / 4; i += 256) w4[i] = W14[i];

    const float4* x4 = (const float4*)x;
    float4* xt4 = (float4*)xt;
    for (int i = tid; i < 16 * F_IN / 4; i += 256) {
        int r = i >> 5;
        int node = node0 + r;
        xt4[i] = (node < N) ? x4[(size_t)node * 32 + (i & 31)]
                            : make_float4(0.f, 0.f, 0.f, 0.f);
    }
    __syncthreads();

    int nsub = tid >> 4, f = tid & 15;
    int node = node0 + nsub;
    if (node < N) {
        const float* xr = xt + nsub * F_IN;
        float acc = 0.0f;
        #pragma unroll 16
        for (int k = 0; k < F_IN; ++k)
            acc = fmaf(xr[k], w[k * H1 + f], acc);
        h1s[node * H1 + f] = acc * dinv[node];
    }
}

// ---- layer 1 aggregation: S segments per bucket, partials out ----
// 4 threads per edge (float4 of h1s), 4x unrolled, loads batched before atomics.
__global__ __launch_bounds__(256) void k_agg1(
    const int* __restrict__ packed, const int* __restrict__ base_e,
    const float* __restrict__ h1s, const float* __restrict__ dinv,
    float* __restrict__ part1, int N, int S) {
    __shared__ float acc[NPB * H1];   // 8 KB
    __shared__ float dl[NPB];
    int bid = blockIdx.x;
    int b = bid / S, seg = bid - b * S;
    int base = b * NPB;
    int t = threadIdx.x;
    if (t < NPB) {
        int node = base + t;
        dl[t] = (node < N) ? dinv[node] : 0.f;
    }
    for (int i = t; i < NPB * H1; i += 256) acc[i] = 0.f;
    __syncthreads();

    int e0 = base_e[b], e1 = base_e[b + 1];
    int len = e1 - e0;
    int segLen = (len + S - 1) / S;
    int es = e0 + seg * segLen;
    int ee = min(es + segLen, e1);

    int g = t >> 2, q = t & 3;
    const float4* h4 = (const float4*)h1s;
    for (int e = es + g; e < ee; e += 256) {
        float4 v[4]; float dvv[4]; int dd[4]; bool ok[4];
        #pragma unroll
        for (int u = 0; u < 4; ++u) {
            int eu = e + u * 64;
            ok[u] = eu < ee;
            unsigned p = ok[u] ? (unsigned)packed[eu] : 0u;
            dd[u] = (p >> 24) & (NPB - 1);
            int s = p & 0xFFFFFF;
            v[u] = ok[u] ? h4[(size_t)s * 4 + q] : make_float4(0.f, 0.f, 0.f, 0.f);
            dvv[u] = dl[dd[u]];
        }
        #pragma unroll
        for (int u = 0; u < 4; ++u) {
            if (ok[u]) {
                float* ap = acc + dd[u] * H1 + q * 4;
                atomicAdd(ap + 0, v[u].x * dvv[u]);
                atomicAdd(ap + 1, v[u].y * dvv[u]);
                atomicAdd(ap + 2, v[u].z * dvv[u]);
                atomicAdd(ap + 3, v[u].w * dvv[u]);
            }
        }
    }
    __syncthreads();
    float4* po = (float4*)(part1 + (size_t)bid * (NPB * H1));
    const float4* ai = (const float4*)acc;
    for (int i = t; i < NPB * H1 / 4; i += 256) po[i] = ai[i];
}

// ---- merge1: sum S partials + self-loop, relu, @W2, pre-scale -> h2s ----
__global__ __launch_bounds__(256) void k_merge1(
    const float* __restrict__ part1, const float* __restrict__ h1s,
    const float* __restrict__ dinv, const float* __restrict__ b1,
    const float* __restrict__ W2, float* __restrict__ h2s, int N, int S) {
    int n = blockIdx.x * 256 + threadIdx.x;
    if (n >= N) return;
    int b = n >> LOG_NPB, d = n & (NPB - 1);
    float dv = dinv[n];
    float a[H1];
    const float4* hh = (const float4*)(h1s + (size_t)n * H1);
    #pragma unroll
    for (int q = 0; q < 4; ++q) {
        float4 v = hh[q];
        a[q*4+0] = v.x * dv; a[q*4+1] = v.y * dv;
        a[q*4+2] = v.z * dv; a[q*4+3] = v.w * dv;
    }
    for (int s = 0; s < S; ++s) {
        const float4* pp = (const float4*)(part1 + ((size_t)(b * S + s) * NPB + d) * H1);
        #pragma unroll
        for (int q = 0; q < 4; ++q) {
            float4 v = pp[q];
            a[q*4+0] += v.x; a[q*4+1] += v.y;
            a[q*4+2] += v.z; a[q*4+3] += v.w;
        }
    }
    float c0 = 0.f, c1 = 0.f;
    #pragma unroll
    for (int f = 0; f < H1; ++f) {
        float v = fmaxf(a[f] + b1[f], 0.f);
        c0 = fmaf(v, W2[f * C_OUT + 0], c0);
        c1 = fmaf(v, W2[f * C_OUT + 1], c1);
    }
    ((float2*)h2s)[n] = make_float2(c0 * dv, c1 * dv);
}

// ---- layer 2 aggregation: S segments per bucket, partials out ----
__global__ __launch_bounds__(256) void k_agg2(
    const int* __restrict__ packed, const int* __restrict__ base_e,
    const float* __restrict__ h2s, const float* __restrict__ dinv,
    float* __restrict__ part2, int N, int S) {
    __shared__ float acc[NPB * 2];
    __shared__ float dl[NPB];
    int bid = blockIdx.x;
    int b = bid / S, seg = bid - b * S;
    int base = b * NPB;
    int t = threadIdx.x;
    if (t < NPB) {
        int node = base + t;
        dl[t] = (node < N) ? dinv[node] : 0.f;
    }
    if (t < NPB * 2) acc[t] = 0.f;
    __syncthreads();

    int e0 = base_e[b], e1 = base_e[b + 1];
    int len = e1 - e0;
    int segLen = (len + S - 1) / S;
    int es = e0 + seg * segLen;
    int ee = min(es + segLen, e1);

    const float2* h2 = (const float2*)h2s;
    for (int e = es + t; e < ee; e += 1024) {
        float2 v[4]; int dd[4]; float dvv[4]; bool ok[4];
        #pragma unroll
        for (int u = 0; u < 4; ++u) {
            int eu = e + u * 256;
            ok[u] = eu < ee;
            unsigned p = ok[u] ? (unsigned)packed[eu] : 0u;
            dd[u] = (p >> 24) & (NPB - 1);
            v[u] = ok[u] ? h2[p & 0xFFFFFF] : make_float2(0.f, 0.f);
            dvv[u] = dl[dd[u]];
        }
        #pragma unroll
        for (int u = 0; u < 4; ++u) {
            if (ok[u]) {
                atomicAdd(&acc[dd[u] * 2 + 0], v[u].x * dvv[u]);
                atomicAdd(&acc[dd[u] * 2 + 1], v[u].y * dvv[u]);
            }
        }
    }
    __syncthreads();
    float2* po = (float2*)(part2 + (size_t)bid * (NPB * 2));
    const float2* ai = (const float2*)acc;
    for (int i = t; i < NPB; i += 256) po[i] = ai[i];
}

// ---- merge2: sum S partials + self-loop, +b2, log_softmax -> out ----
__global__ __launch_bounds__(256) void k_merge2(
    const float* __restrict__ part2, const float* __restrict__ h2s,
    const float* __restrict__ dinv, const float* __restrict__ b2,
    float* __restrict__ out, int N, int S) {
    int n = blockIdx.x * 256 + threadIdx.x;
    if (n >= N) return;
    int b = n >> LOG_NPB, d = n & (NPB - 1);
    float dv = dinv[n];
    float2 h = ((const float2*)h2s)[n];
    float a0 = h.x * dv, a1 = h.y * dv;
    for (int s = 0; s < S; ++s) {
        float2 v = ((const float2*)part2)[(size_t)(b * S + s) * NPB + d];
        a0 += v.x; a1 += v.y;
    }
    a0 += b2[0]; a1 += b2[1];
    float m = fmaxf(a0, a1);
    float lse = m + logf(expf(a0 - m) + expf(a1 - m));
    ((float2*)out)[n] = make_float2(a0 - lse, a1 - lse);
}

extern "C" void kernel_launch(void* const* d_in, const int* in_sizes, int n_in,
                              void* d_out, int out_size, void* d_ws, size_t ws_size,
                              hipStream_t stream) {
    const float* x  = (const float*)d_in[0];
    const int* ei   = (const int*)d_in[1];
    const float* W1 = (const float*)d_in[2];
    const float* b1 = (const float*)d_in[3];
    const float* W2 = (const float*)d_in[4];
    const float* b2 = (const float*)d_in[5];
    float* out = (float*)d_out;

    const int N = in_sizes[0] / F_IN;     // 100000
    const int E = in_sizes[1] / 2;        // 3200000
    const int* src0 = ei;
    const int* dst0 = ei + E;

    const int K = (N + NPB - 1) >> LOG_NPB;      // 782
    const int nblk = (E + CH - 1) / CH;          // 782

    // adaptive segment count based on ws capacity
    size_t fixed_f = (size_t)N * (1 + H1 + C_OUT) + (size_t)E
                   + (size_t)K * nblk + K + (K + 1) + 16 /*alignment slack*/;
    size_t perS_f = (size_t)K * (NPB * H1 + NPB * C_OUT);
    size_t avail_f = ws_size / 4;
    int S = 4;
    while (S > 1 && fixed_f + (size_t)S * perS_f > avail_f) S >>= 1;

    // workspace layout (float units), segments 16B-aligned
    size_t off = 0;
    float* wsf = (float*)d_ws;
    auto take = [&](size_t nf) { float* p = wsf + off; off += (nf + 3) & ~(size_t)3; return p; };
    float* dinv   = take(N);
    float* h1s    = take((size_t)N * H1);
    float* h2s    = take((size_t)N * C_OUT);
    int*   packed = (int*)take(E);
    int*   cnt    = (int*)take((size_t)K * nblk);
    int*   tot    = (int*)take(K);
    int*   base_e = (int*)take(K + 1);
    float* part1  = take((size_t)K * S * NPB * H1);
    float* part2  = take((size_t)K * S * NPB * C_OUT);

    int nbN = (N + 255) / 256;

    k_part_count<<<nblk, 256, 0, stream>>>(dst0, cnt, E, K, nblk);
    k_colscan<<<K, 1024, 0, stream>>>(cnt, tot, nblk);
    k_basescan<<<1, 1024, 0, stream>>>(tot, base_e, K);
    k_scatter<<<nblk, 256, 0, stream>>>(src0, dst0, cnt, base_e, packed, E, K, nblk);
    k_deg<<<K, 1024, 0, stream>>>(packed, base_e, dinv, N);
    k_gemm1<<<(N + 15) / 16, 256, 0, stream>>>(x, W1, dinv, h1s, N);
    k_agg1<<<K * S, 256, 0, stream>>>(packed, base_e, h1s, dinv, part1, N, S);
    k_merge1<<<nbN, 256, 0, stream>>>(part1, h1s, dinv, b1, W2, h2s, N, S);
    k_agg2<<<K * S, 256, 0, stream>>>(packed, base_e, h2s, dinv, part2, N, S);
    k_merge2<<<nbN, 256, 0, stream>>>(part2, h2s, dinv, b2, out, N, S);
}